// Round 6
// baseline (77.347 us; speedup 1.0000x reference)
//
#include <hip/hip_runtime.h>
#include <hip/hip_bf16.h>

// Problem constants (B,T,D,F) = (4,1024,256,128)
#define BT 4096
#define DD 256
#define CAT 129

typedef __attribute__((ext_vector_type(8))) _Float16 f16x8;
typedef __attribute__((ext_vector_type(4))) _Float16 f16x4;
typedef __attribute__((ext_vector_type(2))) _Float16 h2;
typedef __attribute__((ext_vector_type(4))) float f32x4;

static __device__ __forceinline__ h2 cvt_pk(float a, float b) {
    return __builtin_bit_cast(h2, __builtin_amdgcn_cvt_pkrtz(a, b));
}

static __device__ __forceinline__ float fdot2f(h2 a, h2 b, float c) {
#if __has_builtin(__builtin_amdgcn_fdot2)
    return __builtin_amdgcn_fdot2(__builtin_bit_cast(__fp16 __attribute__((ext_vector_type(2))), a),
                                  __builtin_bit_cast(__fp16 __attribute__((ext_vector_type(2))), b),
                                  c, false);
#else
    return fmaf((float)a[0], (float)b[0], fmaf((float)a[1], (float)b[1], c));
#endif
}

// ---------------------------------------------------------------------------
// k_cvt: blocks 0..7: W2 -> f16 LINEAR (consumed from global by k_main).
//        blocks 8..15: W1[:,1:] -> f16 XOR-swizzled (consumed by k_prep2);
//        block 8 also emits w10h, wpah (Wp row0 f16), wpbh (Wp row1 f16).
// ---------------------------------------------------------------------------
__global__ void __launch_bounds__(256) k_cvt(
    const float* __restrict__ W1, const float* __restrict__ W2,
    const float* __restrict__ Wp,
    _Float16* __restrict__ w2h, _Float16* __restrict__ w1h,
    _Float16* __restrict__ w10h, _Float16* __restrict__ wpah,
    _Float16* __restrict__ wpbh)
{
    const int t = threadIdx.x, b = blockIdx.x;
    if (b < 8) {
        #pragma unroll
        for (int i = 0; i < 8; ++i) {
            int idx = b * 2048 + i * 256 + t;       // g*128+f, linear
            w2h[idx] = (_Float16)W2[idx];
        }
    } else {
        int q = b - 8;
        #pragma unroll
        for (int i = 0; i < 8; ++i) {
            int idx = q * 2048 + i * 256 + t;       // f*128+c
            int f = idx >> 7, c = idx & 127;
            w1h[idx ^ ((f & 7) << 3)] = (_Float16)W1[f * CAT + 1 + c];
        }
        if (q == 0 && t < 128) {
            w10h[t] = (_Float16)W1[t * CAT];
            wpah[t] = (_Float16)Wp[t];
            wpbh[t] = (_Float16)Wp[CAT + t];
        }
    }
}

// ---------------------------------------------------------------------------
// k_prep2: v1 = b1 + feature @ W1[:,1:]^T  (f16 MFMA GEMM, 16 rows/block),
// output stored as f16, linear [bt][f].
// ---------------------------------------------------------------------------
__global__ void __launch_bounds__(256) k_prep2(
    const float* __restrict__ feature, const _Float16* __restrict__ w1h,
    const float* __restrict__ b1p, _Float16* __restrict__ v1h)
{
    __shared__ __align__(16) _Float16 fS[2048];   // 16 x 128 f16, swizzled
    const int t = threadIdx.x;
    const int r0 = blockIdx.x * 16;

    {
        int e = t * 8;
        int r = e >> 7, c = e & 127;
        const float4* src = (const float4*)(feature + (size_t)(r0 + r) * 128 + c);
        float4 x0 = src[0], x1 = src[1];
        f16x8 hv;
        hv[0] = (_Float16)x0.x; hv[1] = (_Float16)x0.y;
        hv[2] = (_Float16)x0.z; hv[3] = (_Float16)x0.w;
        hv[4] = (_Float16)x1.x; hv[5] = (_Float16)x1.y;
        hv[6] = (_Float16)x1.z; hv[7] = (_Float16)x1.w;
        *(f16x8*)&fS[e ^ ((r & 7) << 3)] = hv;
    }
    __syncthreads();

    const int lane = t & 63, wv = t >> 6;
    const int l15 = lane & 15, l4 = lane >> 4;

    f16x8 bfr[2][4];
    float4 b1v[2];
    #pragma unroll
    for (int nt = 0; nt < 2; ++nt) {
        const int f0 = wv * 32 + nt * 16;
        b1v[nt] = *(const float4*)(b1p + f0 + l4 * 4);
        #pragma unroll
        for (int kc = 0; kc < 4; ++kc) {
            int f = f0 + l15, c = kc * 32 + l4 * 8;
            bfr[nt][kc] = *(const f16x8*)&w1h[(f * 128 + c) ^ ((f & 7) << 3)];
        }
    }

    const f32x4 fz = {0.f, 0.f, 0.f, 0.f};
    f32x4 acc[2] = {fz, fz};
    #pragma unroll
    for (int kc = 0; kc < 4; ++kc) {
        int r = l15, c = kc * 32 + l4 * 8;
        f16x8 afr = *(const f16x8*)&fS[(r * 128 + c) ^ ((r & 7) << 3)];
        #pragma unroll
        for (int nt = 0; nt < 2; ++nt)
            acc[nt] = __builtin_amdgcn_mfma_f32_16x16x32_f16(
                bfr[nt][kc], afr, acc[nt], 0, 0, 0);
    }

    #pragma unroll
    for (int nt = 0; nt < 2; ++nt) {
        f16x4 o;
        o[0] = (_Float16)(acc[nt][0] + ((const float*)&b1v[nt])[0]);
        o[1] = (_Float16)(acc[nt][1] + ((const float*)&b1v[nt])[1]);
        o[2] = (_Float16)(acc[nt][2] + ((const float*)&b1v[nt])[2]);
        o[3] = (_Float16)(acc[nt][3] + ((const float*)&b1v[nt])[3]);
        *(f16x4*)&v1h[(size_t)(r0 + l15) * 128 + wv * 32 + nt * 16 + l4 * 4] = o;
    }
}

// ---------------------------------------------------------------------------
// k_main: fully LDS-free, barrier-free. Each wave owns a 16-row x 128-col
// output tile: W2 held entirely in registers (bfr[8][4], loaded once per
// wave), h1 B-fragments GENERATED in registers from v1/w10 lane-windows,
// 32 MFMAs per tile in two nt-halves, fused epilogue with L1-hot per-nt
// constant loads + 4-lane shfl reduce + gate + store. 2048 waves x 32 tiles.
// ---------------------------------------------------------------------------
__global__ void __launch_bounds__(256, 2) k_main(
    const float* __restrict__ inp, const float* __restrict__ b2p,
    const float* __restrict__ Wp, const float* __restrict__ bpp,
    const float* __restrict__ a1p, const float* __restrict__ a2p,
    const _Float16* __restrict__ v1h, const _Float16* __restrict__ w2h,
    const _Float16* __restrict__ w10h, const _Float16* __restrict__ wpah,
    const _Float16* __restrict__ wpbh, float* __restrict__ out)
{
    const int tid  = threadIdx.x;
    const int lane = tid & 63, wv = tid >> 6;
    const int l15  = lane & 15, l4 = lane >> 4;
    const int w    = blockIdx.x * 4 + wv;     // global wave id 0..2047
    const int bt0  = w * 2;                   // this wave handles bt0, bt0+1

    // ---- persistent W2 fragments: lane holds W2[g=nt*16+l15][f-window] ----
    f16x8 bfr[8][4];
    #pragma unroll
    for (int nt = 0; nt < 8; ++nt)
        #pragma unroll
        for (int kc = 0; kc < 4; ++kc)
            bfr[nt][kc] = *(const f16x8*)
                &w2h[(nt * 16 + l15) * 128 + kc * 32 + l4 * 8];

    // ---- w10 lane-window (fixed f = kc*32 + l4*8 .. +8) ----
    f16x8 w10pk[4];
    #pragma unroll
    for (int kc = 0; kc < 4; ++kc)
        w10pk[kc] = *(const f16x8*)&w10h[kc * 32 + l4 * 8];

    // ---- scalars ----
    const _Float16 a1s = (_Float16)a1p[0];
    const _Float16 a2s = (_Float16)a2p[0];
    f16x8 a1x8 = {a1s, a1s, a1s, a1s, a1s, a1s, a1s, a1s};
    h2 a2v; a2v[0] = a2s; a2v[1] = a2s;
    f16x8 z8 = {(_Float16)0.f, (_Float16)0.f, (_Float16)0.f, (_Float16)0.f,
                (_Float16)0.f, (_Float16)0.f, (_Float16)0.f, (_Float16)0.f};
    h2 z2; z2[0] = (_Float16)0.f; z2[1] = (_Float16)0.f;
    const float wpi0 = Wp[128], wpi1 = Wp[CAT + 128];
    const float bp0  = bpp[0],  bp1  = bpp[1];
    const f32x4 fz = {0.f, 0.f, 0.f, 0.f};

    f16x8 v1pk[4];
    float s_cur = inp[(size_t)bt0 * DD + l15];   // tile 0 row value

    #pragma unroll 2
    for (int ii = 0; ii < 32; ++ii) {
        const int bt = bt0 + (ii >> 4), rb = ii & 15;

        if ((ii & 15) == 0) {   // new bt: reload v1 lane-window
            #pragma unroll
            for (int kc = 0; kc < 4; ++kc)
                v1pk[kc] = *(const f16x8*)
                    &v1h[(size_t)bt * 128 + kc * 32 + l4 * 8];
        }

        const float s_row = s_cur;
        // prefetch next tile's s (hidden under afr-gen + MFMA)
        if (ii < 31) {
            const int jj = ii + 1;
            s_cur = inp[(size_t)(bt0 + (jj >> 4)) * DD + (jj & 15) * 16 + l15];
        }

        // ---- h1 B-fragments generated in registers ----
        const _Float16 sh = (_Float16)s_row;
        f16x8 s8 = {sh, sh, sh, sh, sh, sh, sh, sh};
        f16x8 afr[4];
        #pragma unroll
        for (int kc = 0; kc < 4; ++kc) {
            f16x8 h = v1pk[kc] + w10pk[kc] * s8;
            afr[kc] = __builtin_elementwise_max(h, z8)
                    + a1x8 * __builtin_elementwise_min(h, z8);
        }

        // ---- 32 MFMAs in two nt-halves + fused epilogue ----
        float s0 = 0.f, s1 = 0.f;
        #pragma unroll
        for (int hf = 0; hf < 2; ++hf) {
            f32x4 acc[4] = {fz, fz, fz, fz};
            #pragma unroll
            for (int kc = 0; kc < 4; ++kc)
                #pragma unroll
                for (int q = 0; q < 4; ++q)
                    acc[q] = __builtin_amdgcn_mfma_f32_16x16x32_f16(
                        bfr[hf * 4 + q][kc], afr[kc], acc[q], 0, 0, 0);

            #pragma unroll
            for (int q = 0; q < 4; ++q) {
                const int g0 = (hf * 4 + q) * 16 + l4 * 4;
                const float4 b2v = *(const float4*)&b2p[g0];
                const f16x4 wa = *(const f16x4*)&wpah[g0];
                const f16x4 wb = *(const f16x4*)&wpbh[g0];
                h2 hh0 = cvt_pk(acc[q][0] + b2v.x, acc[q][1] + b2v.y);
                h2 hh1 = cvt_pk(acc[q][2] + b2v.z, acc[q][3] + b2v.w);
                h2 hp0 = __builtin_elementwise_max(hh0, z2)
                       + a2v * __builtin_elementwise_min(hh0, z2);
                h2 hp1 = __builtin_elementwise_max(hh1, z2)
                       + a2v * __builtin_elementwise_min(hh1, z2);
                h2 wa0; wa0[0] = wa[0]; wa0[1] = wa[1];
                h2 wa1; wa1[0] = wa[2]; wa1[1] = wa[3];
                h2 wb0; wb0[0] = wb[0]; wb0[1] = wb[1];
                h2 wb1; wb1[0] = wb[2]; wb1[1] = wb[3];
                s0 = fdot2f(wa0, hp0, s0); s0 = fdot2f(wa1, hp1, s0);
                s1 = fdot2f(wb0, hp0, s1); s1 = fdot2f(wb1, hp1, s1);
            }
        }

        // ---- reduce over l4 (4 lanes, stride 16) ----
        s0 += __shfl_xor(s0, 16); s0 += __shfl_xor(s0, 32);
        s1 += __shfl_xor(s1, 16); s1 += __shfl_xor(s1, 32);

        if (l4 == 0) {
            const float e0 = s0 + wpi0 * s_row + bp0;
            const float e1 = s1 + wpi1 * s_row + bp1;
            const float gg = e0 / (1.f + __expf(-e1));
            out[(size_t)bt * DD + rb * 16 + l15] = s_row * (1.f + gg);
        }
    }
}

// ---------------------------------------------------------------------------
extern "C" void kernel_launch(void* const* d_in, const int* in_sizes, int n_in,
                              void* d_out, int out_size, void* d_ws, size_t ws_size,
                              hipStream_t stream)
{
    (void)in_sizes; (void)n_in; (void)out_size; (void)ws_size;
    const float* input   = (const float*)d_in[0];
    const float* feature = (const float*)d_in[1];
    // d_in[2] slider: unused by the reference computation
    const float* W1 = (const float*)d_in[3];
    const float* b1 = (const float*)d_in[4];
    const float* a1 = (const float*)d_in[5];
    const float* W2 = (const float*)d_in[6];
    const float* b2 = (const float*)d_in[7];
    const float* a2 = (const float*)d_in[8];
    const float* Wp = (const float*)d_in[9];
    const float* bp = (const float*)d_in[10];
    float* out = (float*)d_out;

    // workspace: v1h 1MB | w2h 32KB | w1h 32KB | w10h 256B | wpah 256B | wpbh 256B
    _Float16* v1h  = (_Float16*)d_ws;
    _Float16* w2h  = v1h + (size_t)BT * 128;
    _Float16* w1h  = w2h + 16384;
    _Float16* w10h = w1h + 16384;
    _Float16* wpah = w10h + 128;
    _Float16* wpbh = wpah + 128;

    k_cvt  <<<dim3(16),  dim3(256), 0, stream>>>(W1, W2, Wp, w2h, w1h,
                                                 w10h, wpah, wpbh);
    k_prep2<<<dim3(256), dim3(256), 0, stream>>>(feature, w1h, b1, v1h);
    k_main <<<dim3(512), dim3(256), 0, stream>>>(input, b2, Wp, bp, a1, a2,
                                                 v1h, w2h, w10h, wpah, wpbh, out);
}

// Round 7
// 71.602 us; speedup vs baseline: 1.0802x; 1.0802x over previous
//
#include <hip/hip_runtime.h>
#include <hip/hip_bf16.h>

// Problem constants (B,T,D,F) = (4,1024,256,128)
#define BT 4096
#define DD 256
#define CAT 129

typedef __attribute__((ext_vector_type(8))) _Float16 f16x8;
typedef __attribute__((ext_vector_type(4))) _Float16 f16x4;
typedef __attribute__((ext_vector_type(2))) _Float16 h2;
typedef __attribute__((ext_vector_type(4))) float f32x4;

static __device__ __forceinline__ h2 cvt_pk(float a, float b) {
    return __builtin_bit_cast(h2, __builtin_amdgcn_cvt_pkrtz(a, b));
}

static __device__ __forceinline__ float fdot2f(h2 a, h2 b, float c) {
#if __has_builtin(__builtin_amdgcn_fdot2)
    return __builtin_amdgcn_fdot2(__builtin_bit_cast(__fp16 __attribute__((ext_vector_type(2))), a),
                                  __builtin_bit_cast(__fp16 __attribute__((ext_vector_type(2))), b),
                                  c, false);
#else
    return fmaf((float)a[0], (float)b[0], fmaf((float)a[1], (float)b[1], c));
#endif
}

// ---------------------------------------------------------------------------
// k_cvt: blocks 0..7: W2 -> f16 LINEAR (lane-fragment reads in k_main).
//        blocks 8..15: W1[:,1:] -> f16 XOR-swizzled (for k_prep2);
//        block 8 also emits w10h = W1[:,0] in f16.
// ---------------------------------------------------------------------------
__global__ void __launch_bounds__(256) k_cvt(
    const float* __restrict__ W1, const float* __restrict__ W2,
    _Float16* __restrict__ w2h, _Float16* __restrict__ w1h,
    _Float16* __restrict__ w10h)
{
    const int t = threadIdx.x, b = blockIdx.x;
    if (b < 8) {
        #pragma unroll
        for (int i = 0; i < 8; ++i) {
            int idx = b * 2048 + i * 256 + t;       // g*128+f, linear
            w2h[idx] = (_Float16)W2[idx];
        }
    } else {
        int q = b - 8;
        #pragma unroll
        for (int i = 0; i < 8; ++i) {
            int idx = q * 2048 + i * 256 + t;       // f*128+c
            int f = idx >> 7, c = idx & 127;
            w1h[idx ^ ((f & 7) << 3)] = (_Float16)W1[f * CAT + 1 + c];
        }
        if (q == 0 && t < 128) w10h[t] = (_Float16)W1[t * CAT];
    }
}

// ---------------------------------------------------------------------------
// k_prep2: v1 = b1 + feature @ W1[:,1:]^T  (f16 MFMA GEMM, 16 rows/block),
// output stored as f16, linear [bt][f].
// ---------------------------------------------------------------------------
__global__ void __launch_bounds__(256) k_prep2(
    const float* __restrict__ feature, const _Float16* __restrict__ w1h,
    const float* __restrict__ b1p, _Float16* __restrict__ v1h)
{
    __shared__ __align__(16) _Float16 fS[2048];   // 16 x 128 f16, swizzled
    const int t = threadIdx.x;
    const int r0 = blockIdx.x * 16;

    {
        int e = t * 8;
        int r = e >> 7, c = e & 127;
        const float4* src = (const float4*)(feature + (size_t)(r0 + r) * 128 + c);
        float4 x0 = src[0], x1 = src[1];
        f16x8 hv;
        hv[0] = (_Float16)x0.x; hv[1] = (_Float16)x0.y;
        hv[2] = (_Float16)x0.z; hv[3] = (_Float16)x0.w;
        hv[4] = (_Float16)x1.x; hv[5] = (_Float16)x1.y;
        hv[6] = (_Float16)x1.z; hv[7] = (_Float16)x1.w;
        *(f16x8*)&fS[e ^ ((r & 7) << 3)] = hv;
    }
    __syncthreads();

    const int lane = t & 63, wv = t >> 6;
    const int l15 = lane & 15, l4 = lane >> 4;

    f16x8 bfr[2][4];
    float4 b1v[2];
    #pragma unroll
    for (int nt = 0; nt < 2; ++nt) {
        const int f0 = wv * 32 + nt * 16;
        b1v[nt] = *(const float4*)(b1p + f0 + l4 * 4);
        #pragma unroll
        for (int kc = 0; kc < 4; ++kc) {
            int f = f0 + l15, c = kc * 32 + l4 * 8;
            bfr[nt][kc] = *(const f16x8*)&w1h[(f * 128 + c) ^ ((f & 7) << 3)];
        }
    }

    const f32x4 fz = {0.f, 0.f, 0.f, 0.f};
    f32x4 acc[2] = {fz, fz};
    #pragma unroll
    for (int kc = 0; kc < 4; ++kc) {
        int r = l15, c = kc * 32 + l4 * 8;
        f16x8 afr = *(const f16x8*)&fS[(r * 128 + c) ^ ((r & 7) << 3)];
        #pragma unroll
        for (int nt = 0; nt < 2; ++nt)
            acc[nt] = __builtin_amdgcn_mfma_f32_16x16x32_f16(
                bfr[nt][kc], afr, acc[nt], 0, 0, 0);
    }

    #pragma unroll
    for (int nt = 0; nt < 2; ++nt) {
        f16x4 o;
        o[0] = (_Float16)(acc[nt][0] + ((const float*)&b1v[nt])[0]);
        o[1] = (_Float16)(acc[nt][1] + ((const float*)&b1v[nt])[1]);
        o[2] = (_Float16)(acc[nt][2] + ((const float*)&b1v[nt])[2]);
        o[3] = (_Float16)(acc[nt][3] + ((const float*)&b1v[nt])[3]);
        *(f16x4*)&v1h[(size_t)(r0 + l15) * 128 + wv * 32 + nt * 16 + l4 * 4] = o;
    }
}

// ---------------------------------------------------------------------------
// k_main: hybrid structure. 512 threads = 8 waves (2 rg x 4 cg), 2 bt/block.
// Wave holds W2 cols [cg*32, cg*32+32) as bfr[2][4] (32 VGPR) and generates
// the h1 B-fragments IN REGISTERS from v1/w10 lane-windows (no h1 LDS at
// all). b2 pre-folded into MFMA C-init; prelu via max(h, a*h) (a in [0,1]).
// 1 barrier/quarter; rotating-wave final overlaps the other waves' next
// quarter. VGPR budget ~124, enforced <=128 by __launch_bounds__(512,4).
// ---------------------------------------------------------------------------
__global__ void __launch_bounds__(512, 4) k_main(
    const float* __restrict__ inp, const float* __restrict__ b2p,
    const float* __restrict__ Wp, const float* __restrict__ bpp,
    const float* __restrict__ a1p, const float* __restrict__ a2p,
    const _Float16* __restrict__ v1h, const _Float16* __restrict__ w2h,
    const _Float16* __restrict__ w10h, float* __restrict__ out)
{
    __shared__ float inps[512];          // 2 bt rows of input
    __shared__ float2 prs[2][4][64];     // double-buffered partials, 4 KB

    const int tid  = threadIdx.x;
    const int lane = tid & 63, wv = tid >> 6;
    const int rg   = wv >> 2, cg = wv & 3;
    const int l15  = lane & 15, l4 = lane >> 4;
    const int bt0  = blockIdx.x * 2;

    inps[tid] = inp[(size_t)bt0 * DD + tid];

    // ---- W2 fragments: lane holds W2[g = cg*32+nt*16+l15][f-window] ----
    f16x8 bfr[2][4];
    #pragma unroll
    for (int nt = 0; nt < 2; ++nt)
        #pragma unroll
        for (int kc = 0; kc < 4; ++kc)
            bfr[nt][kc] = *(const f16x8*)
                &w2h[(cg * 32 + nt * 16 + l15) * 128 + kc * 32 + l4 * 8];

    // ---- w10 lane-window (fixed f = kc*32 + l4*8 .. +8) ----
    f16x8 w10pk[4];
    #pragma unroll
    for (int kc = 0; kc < 4; ++kc)
        w10pk[kc] = *(const f16x8*)&w10h[kc * 32 + l4 * 8];

    // ---- scalars (a1,a2 in [0,1] per setup: prelu(x)=max(x,a*x)) ----
    const _Float16 a1s = (_Float16)a1p[0];
    const _Float16 a2s = (_Float16)a2p[0];
    f16x8 a1x8 = {a1s, a1s, a1s, a1s, a1s, a1s, a1s, a1s};
    h2 a2v; a2v[0] = a2s; a2v[1] = a2s;
    const float wpi0 = Wp[128], wpi1 = Wp[CAT + 128];
    const float bp0  = bpp[0],  bp1  = bpp[1];

    // ---- b2 pre-fold (C-init) + packed Wp slices ----
    f32x4 accInit[2];
    h2 wpa_pk[2][2], wpb_pk[2][2];
    #pragma unroll
    for (int nt = 0; nt < 2; ++nt) {
        const int g0 = cg * 32 + nt * 16 + l4 * 4;
        accInit[nt][0] = b2p[g0];     accInit[nt][1] = b2p[g0 + 1];
        accInit[nt][2] = b2p[g0 + 2]; accInit[nt][3] = b2p[g0 + 3];
        wpa_pk[nt][0] = cvt_pk(Wp[g0],           Wp[g0 + 1]);
        wpa_pk[nt][1] = cvt_pk(Wp[g0 + 2],       Wp[g0 + 3]);
        wpb_pk[nt][0] = cvt_pk(Wp[CAT + g0],     Wp[CAT + g0 + 1]);
        wpb_pk[nt][1] = cvt_pk(Wp[CAT + g0 + 2], Wp[CAT + g0 + 3]);
    }
    __syncthreads();

    f16x8 v1pk[4];

    #pragma unroll 2
    for (int i = 0; i < 8; ++i) {
        const int btl = i >> 2, qt = i & 3, buf = i & 1;

        if ((i & 3) == 0) {   // new bt: reload v1 lane-window
            #pragma unroll
            for (int kc = 0; kc < 4; ++kc)
                v1pk[kc] = *(const f16x8*)
                    &v1h[(size_t)(bt0 + btl) * 128 + kc * 32 + l4 * 8];
        }

        // ---- rows for this wave: r = rg*32 + rt*16 + l15 ----
        const int rbase = btl * 256 + qt * 64 + rg * 32;
        const float s0f = inps[rbase + l15];
        const float s1f = inps[rbase + 16 + l15];
        const _Float16 sh0 = (_Float16)s0f, sh1 = (_Float16)s1f;
        f16x8 s8a = {sh0, sh0, sh0, sh0, sh0, sh0, sh0, sh0};
        f16x8 s8b = {sh1, sh1, sh1, sh1, sh1, sh1, sh1, sh1};

        // ---- MFMA with in-register B-fragment generation ----
        f32x4 acc[2][2];
        acc[0][0] = accInit[0]; acc[0][1] = accInit[0];
        acc[1][0] = accInit[1]; acc[1][1] = accInit[1];

        #pragma unroll
        for (int kc = 0; kc < 4; ++kc) {
            f16x8 h0 = v1pk[kc] + w10pk[kc] * s8a;
            f16x8 af0 = __builtin_elementwise_max(h0, a1x8 * h0);
            f16x8 h1 = v1pk[kc] + w10pk[kc] * s8b;
            f16x8 af1 = __builtin_elementwise_max(h1, a1x8 * h1);
            #pragma unroll
            for (int nt = 0; nt < 2; ++nt) {
                acc[nt][0] = __builtin_amdgcn_mfma_f32_16x16x32_f16(
                    bfr[nt][kc], af0, acc[nt][0], 0, 0, 0);
                acc[nt][1] = __builtin_amdgcn_mfma_f32_16x16x32_f16(
                    bfr[nt][kc], af1, acc[nt][1], 0, 0, 0);
            }
        }

        // ---- packed epilogue: prelu(a2) + Wp dots + l4-reduce ----
        #pragma unroll
        for (int rt = 0; rt < 2; ++rt) {
            float p0 = 0.f, p1 = 0.f;
            #pragma unroll
            for (int nt = 0; nt < 2; ++nt) {
                h2 hh0 = cvt_pk(acc[nt][rt][0], acc[nt][rt][1]);
                h2 hh1 = cvt_pk(acc[nt][rt][2], acc[nt][rt][3]);
                h2 hp0 = __builtin_elementwise_max(hh0, a2v * hh0);
                h2 hp1 = __builtin_elementwise_max(hh1, a2v * hh1);
                p0 = fdot2f(wpa_pk[nt][0], hp0, p0);
                p0 = fdot2f(wpa_pk[nt][1], hp1, p0);
                p1 = fdot2f(wpb_pk[nt][0], hp0, p1);
                p1 = fdot2f(wpb_pk[nt][1], hp1, p1);
            }
            p0 += __shfl_xor(p0, 16); p0 += __shfl_xor(p0, 32);
            p1 += __shfl_xor(p1, 16); p1 += __shfl_xor(p1, 32);
            if (l4 == 0) {
                float2 v; v.x = p0; v.y = p1;
                prs[buf][cg][rg * 32 + rt * 16 + l15] = v;
            }
        }
        __syncthreads();

        // ---- final for THIS quarter on wave i (overlaps next quarter) ----
        if (wv == i) {
            const float s = inps[btl * 256 + qt * 64 + lane];
            const float2 t0 = prs[buf][0][lane], t1 = prs[buf][1][lane];
            const float2 t2 = prs[buf][2][lane], t3 = prs[buf][3][lane];
            const float e0 = t0.x + t1.x + t2.x + t3.x + wpi0 * s + bp0;
            const float e1 = t0.y + t1.y + t2.y + t3.y + wpi1 * s + bp1;
            const float gg = e0 / (1.f + __expf(-e1));
            out[(size_t)(bt0 + btl) * DD + qt * 64 + lane] = s * (1.f + gg);
        }
    }
}

// ---------------------------------------------------------------------------
extern "C" void kernel_launch(void* const* d_in, const int* in_sizes, int n_in,
                              void* d_out, int out_size, void* d_ws, size_t ws_size,
                              hipStream_t stream)
{
    (void)in_sizes; (void)n_in; (void)out_size; (void)ws_size;
    const float* input   = (const float*)d_in[0];
    const float* feature = (const float*)d_in[1];
    // d_in[2] slider: unused by the reference computation
    const float* W1 = (const float*)d_in[3];
    const float* b1 = (const float*)d_in[4];
    const float* a1 = (const float*)d_in[5];
    const float* W2 = (const float*)d_in[6];
    const float* b2 = (const float*)d_in[7];
    const float* a2 = (const float*)d_in[8];
    const float* Wp = (const float*)d_in[9];
    const float* bp = (const float*)d_in[10];
    float* out = (float*)d_out;

    // workspace: v1h 1MB | w2h 32KB | w1h 32KB | w10h 256B
    _Float16* v1h  = (_Float16*)d_ws;
    _Float16* w2h  = v1h + (size_t)BT * 128;
    _Float16* w1h  = w2h + 16384;
    _Float16* w10h = w1h + 16384;

    k_cvt  <<<dim3(16),   dim3(256), 0, stream>>>(W1, W2, w2h, w1h, w10h);
    k_prep2<<<dim3(256),  dim3(256), 0, stream>>>(feature, w1h, b1, v1h);
    k_main <<<dim3(2048), dim3(512), 0, stream>>>(input, b2, Wp, bp, a1, a2,
                                                  v1h, w2h, w10h, out);
}

// Round 8
// 68.748 us; speedup vs baseline: 1.1251x; 1.0415x over previous
//
#include <hip/hip_runtime.h>
#include <hip/hip_bf16.h>

// Problem constants (B,T,D,F) = (4,1024,256,128)
#define BT 4096
#define DD 256
#define CAT 129

typedef __attribute__((ext_vector_type(8))) _Float16 f16x8;
typedef __attribute__((ext_vector_type(4))) _Float16 f16x4;
typedef __attribute__((ext_vector_type(2))) _Float16 h2;
typedef __attribute__((ext_vector_type(4))) float f32x4;

static __device__ __forceinline__ h2 cvt_pk(float a, float b) {
    return __builtin_bit_cast(h2, __builtin_amdgcn_cvt_pkrtz(a, b));
}

static __device__ __forceinline__ float fdot2f(h2 a, h2 b, float c) {
#if __has_builtin(__builtin_amdgcn_fdot2)
    return __builtin_amdgcn_fdot2(__builtin_bit_cast(__fp16 __attribute__((ext_vector_type(2))), a),
                                  __builtin_bit_cast(__fp16 __attribute__((ext_vector_type(2))), b),
                                  c, false);
#else
    return fmaf((float)a[0], (float)b[0], fmaf((float)a[1], (float)b[1], c));
#endif
}

// ---------------------------------------------------------------------------
// k_cvt: blocks 0..7: W2 -> f16 LINEAR. blocks 8..15: W1[:,1:] -> f16
// XOR-swizzled (for k_prep2); block 8 also emits w10h = W1[:,0] in f16.
// ---------------------------------------------------------------------------
__global__ void __launch_bounds__(256) k_cvt(
    const float* __restrict__ W1, const float* __restrict__ W2,
    _Float16* __restrict__ w2h, _Float16* __restrict__ w1h,
    _Float16* __restrict__ w10h)
{
    const int t = threadIdx.x, b = blockIdx.x;
    if (b < 8) {
        #pragma unroll
        for (int i = 0; i < 8; ++i) {
            int idx = b * 2048 + i * 256 + t;       // g*128+f, linear
            w2h[idx] = (_Float16)W2[idx];
        }
    } else {
        int q = b - 8;
        #pragma unroll
        for (int i = 0; i < 8; ++i) {
            int idx = q * 2048 + i * 256 + t;       // f*128+c
            int f = idx >> 7, c = idx & 127;
            w1h[idx ^ ((f & 7) << 3)] = (_Float16)W1[f * CAT + 1 + c];
        }
        if (q == 0 && t < 128) w10h[t] = (_Float16)W1[t * CAT];
    }
}

// ---------------------------------------------------------------------------
// k_prep2: v1 = b1 + feature @ W1[:,1:]^T  (f16 MFMA GEMM, 16 rows/block),
// output stored as f16, linear [bt][f].
// ---------------------------------------------------------------------------
__global__ void __launch_bounds__(256) k_prep2(
    const float* __restrict__ feature, const _Float16* __restrict__ w1h,
    const float* __restrict__ b1p, _Float16* __restrict__ v1h)
{
    __shared__ __align__(16) _Float16 fS[2048];   // 16 x 128 f16, swizzled
    const int t = threadIdx.x;
    const int r0 = blockIdx.x * 16;

    {
        int e = t * 8;
        int r = e >> 7, c = e & 127;
        const float4* src = (const float4*)(feature + (size_t)(r0 + r) * 128 + c);
        float4 x0 = src[0], x1 = src[1];
        f16x8 hv;
        hv[0] = (_Float16)x0.x; hv[1] = (_Float16)x0.y;
        hv[2] = (_Float16)x0.z; hv[3] = (_Float16)x0.w;
        hv[4] = (_Float16)x1.x; hv[5] = (_Float16)x1.y;
        hv[6] = (_Float16)x1.z; hv[7] = (_Float16)x1.w;
        *(f16x8*)&fS[e ^ ((r & 7) << 3)] = hv;
    }
    __syncthreads();

    const int lane = t & 63, wv = t >> 6;
    const int l15 = lane & 15, l4 = lane >> 4;

    f16x8 bfr[2][4];
    float4 b1v[2];
    #pragma unroll
    for (int nt = 0; nt < 2; ++nt) {
        const int f0 = wv * 32 + nt * 16;
        b1v[nt] = *(const float4*)(b1p + f0 + l4 * 4);
        #pragma unroll
        for (int kc = 0; kc < 4; ++kc) {
            int f = f0 + l15, c = kc * 32 + l4 * 8;
            bfr[nt][kc] = *(const f16x8*)&w1h[(f * 128 + c) ^ ((f & 7) << 3)];
        }
    }

    const f32x4 fz = {0.f, 0.f, 0.f, 0.f};
    f32x4 acc[2] = {fz, fz};
    #pragma unroll
    for (int kc = 0; kc < 4; ++kc) {
        int r = l15, c = kc * 32 + l4 * 8;
        f16x8 afr = *(const f16x8*)&fS[(r * 128 + c) ^ ((r & 7) << 3)];
        #pragma unroll
        for (int nt = 0; nt < 2; ++nt)
            acc[nt] = __builtin_amdgcn_mfma_f32_16x16x32_f16(
                bfr[nt][kc], afr, acc[nt], 0, 0, 0);
    }

    #pragma unroll
    for (int nt = 0; nt < 2; ++nt) {
        f16x4 o;
        o[0] = (_Float16)(acc[nt][0] + ((const float*)&b1v[nt])[0]);
        o[1] = (_Float16)(acc[nt][1] + ((const float*)&b1v[nt])[1]);
        o[2] = (_Float16)(acc[nt][2] + ((const float*)&b1v[nt])[2]);
        o[3] = (_Float16)(acc[nt][3] + ((const float*)&b1v[nt])[3]);
        *(f16x4*)&v1h[(size_t)(r0 + l15) * 128 + wv * 32 + nt * 16 + l4 * 4] = o;
    }
}

// ---------------------------------------------------------------------------
// k_main: BARRIER-FREE, LDS-FREE. 8192 independent waves; wave W handles
// (bt = W>>1, cg = W&1): 16 iters of 16 rows x 64 g-cols. Per wave (regs):
// W2 frags bfr[4][4] (64 VGPR), v1/w10 lane-windows (32), packed b2/Wp
// consts (24). Per iter: in-reg h1 B-frag gen -> 16 MFMA -> packed epilogue
// -> 2-shfl in-wave reduce -> one packed-f16 (p0,p1) u32 partial store.
// k_fin combines the two cg halves. No __syncthreads anywhere.
// ---------------------------------------------------------------------------
__global__ void __launch_bounds__(256, 3) k_main(
    const float* __restrict__ inp, const float* __restrict__ b2p,
    const float* __restrict__ Wp, const float* __restrict__ a1p,
    const float* __restrict__ a2p, const _Float16* __restrict__ v1h,
    const _Float16* __restrict__ w2h, const _Float16* __restrict__ w10h,
    unsigned* __restrict__ pr)
{
    const int tid  = threadIdx.x;
    const int lane = tid & 63, wv = tid >> 6;
    const int l15  = lane & 15, l4 = lane >> 4;
    const int W    = blockIdx.x * 4 + wv;     // 0..8191
    const int cg   = W & 1, bt = W >> 1;

    // ---- persistent W2 fragments: g = cg*64 + nt*16 + l15, f-window l4 ----
    f16x8 bfr[4][4];
    #pragma unroll
    for (int nt = 0; nt < 4; ++nt)
        #pragma unroll
        for (int kc = 0; kc < 4; ++kc)
            bfr[nt][kc] = *(const f16x8*)
                &w2h[(cg * 64 + nt * 16 + l15) * 128 + kc * 32 + l4 * 8];

    // ---- v1 / w10 lane-windows (f = kc*32 + l4*8 .. +8) ----
    f16x8 v1pk[4], w10pk[4];
    #pragma unroll
    for (int kc = 0; kc < 4; ++kc) {
        v1pk[kc]  = *(const f16x8*)&v1h[(size_t)bt * 128 + kc * 32 + l4 * 8];
        w10pk[kc] = *(const f16x8*)&w10h[kc * 32 + l4 * 8];
    }

    // ---- packed epilogue constants for this wave's g-range ----
    h2 b2pk[4][2], wpapk[4][2], wpbpk[4][2];
    #pragma unroll
    for (int nt = 0; nt < 4; ++nt) {
        const int g0 = cg * 64 + nt * 16 + l4 * 4;
        const float4 bv = *(const float4*)&b2p[g0];
        const float4 wa = *(const float4*)&Wp[g0];
        b2pk[nt][0]  = cvt_pk(bv.x, bv.y);  b2pk[nt][1]  = cvt_pk(bv.z, bv.w);
        wpapk[nt][0] = cvt_pk(wa.x, wa.y);  wpapk[nt][1] = cvt_pk(wa.z, wa.w);
        wpbpk[nt][0] = cvt_pk(Wp[CAT + g0],     Wp[CAT + g0 + 1]);
        wpbpk[nt][1] = cvt_pk(Wp[CAT + g0 + 2], Wp[CAT + g0 + 3]);
    }

    const _Float16 a1s = (_Float16)a1p[0];
    const _Float16 a2s = (_Float16)a2p[0];
    const f16x8 a1x8 = {a1s, a1s, a1s, a1s, a1s, a1s, a1s, a1s};
    h2 a2v; a2v[0] = a2s; a2v[1] = a2s;
    const f32x4 fz = {0.f, 0.f, 0.f, 0.f};

    const float* srow = inp + (size_t)bt * DD;
    float s_cur = srow[l15];

    #pragma unroll 2
    for (int it = 0; it < 16; ++it) {
        const float s_row = s_cur;
        if (it < 15) s_cur = srow[(it + 1) * 16 + l15];   // prefetch next

        // ---- h1 B-fragments generated in registers ----
        const _Float16 sh = (_Float16)s_row;
        const f16x8 s8 = {sh, sh, sh, sh, sh, sh, sh, sh};

        f32x4 acc[4] = {fz, fz, fz, fz};
        #pragma unroll
        for (int kc = 0; kc < 4; ++kc) {
            f16x8 h  = v1pk[kc] + w10pk[kc] * s8;
            f16x8 af = __builtin_elementwise_max(h, a1x8 * h);   // prelu, a1>=0
            #pragma unroll
            for (int nt = 0; nt < 4; ++nt)
                acc[nt] = __builtin_amdgcn_mfma_f32_16x16x32_f16(
                    bfr[nt][kc], af, acc[nt], 0, 0, 0);
        }

        // ---- packed epilogue: +b2, prelu(a2), Wp dots ----
        float p0 = 0.f, p1 = 0.f;
        #pragma unroll
        for (int nt = 0; nt < 4; ++nt) {
            h2 hh0 = cvt_pk(acc[nt][0], acc[nt][1]) + b2pk[nt][0];
            h2 hh1 = cvt_pk(acc[nt][2], acc[nt][3]) + b2pk[nt][1];
            h2 hp0 = __builtin_elementwise_max(hh0, a2v * hh0);
            h2 hp1 = __builtin_elementwise_max(hh1, a2v * hh1);
            p0 = fdot2f(wpapk[nt][0], hp0, p0);
            p0 = fdot2f(wpapk[nt][1], hp1, p0);
            p1 = fdot2f(wpbpk[nt][0], hp0, p1);
            p1 = fdot2f(wpbpk[nt][1], hp1, p1);
        }

        // ---- in-wave reduce over l4 (4 lanes, stride 16) ----
        p0 += __shfl_xor(p0, 16); p0 += __shfl_xor(p0, 32);
        p1 += __shfl_xor(p1, 16); p1 += __shfl_xor(p1, 32);

        if (l4 == 0)   // one packed f16 (p0,p1) per row per cg-half
            pr[((size_t)bt * DD + it * 16 + l15) * 2 + cg] =
                __builtin_bit_cast(unsigned, cvt_pk(p0, p1));
    }
}

// ---------------------------------------------------------------------------
// k_fin: combine cg halves + wpi*s + bp, sigmoid gate, write out. BW-bound.
// ---------------------------------------------------------------------------
__global__ void __launch_bounds__(256) k_fin(
    const float* __restrict__ inp, const float* __restrict__ Wp,
    const float* __restrict__ bpp, const unsigned* __restrict__ pr,
    float* __restrict__ out)
{
    const int i = blockIdx.x * 256 + threadIdx.x;   // 0 .. BT*DD-1
    const float wpi0 = Wp[128], wpi1 = Wp[CAT + 128];
    const float bp0  = bpp[0],  bp1  = bpp[1];

    const uint2 v = ((const uint2*)pr)[i];
    const h2 pa = __builtin_bit_cast(h2, v.x);   // cg0: (p0, p1)
    const h2 pb = __builtin_bit_cast(h2, v.y);   // cg1: (p0, p1)
    const float s = inp[i];

    const float e0 = (float)pa[0] + (float)pb[0] + wpi0 * s + bp0;
    const float e1 = (float)pa[1] + (float)pb[1] + wpi1 * s + bp1;
    const float gg = e0 / (1.f + __expf(-e1));
    out[i] = s * (1.f + gg);
}

// ---------------------------------------------------------------------------
extern "C" void kernel_launch(void* const* d_in, const int* in_sizes, int n_in,
                              void* d_out, int out_size, void* d_ws, size_t ws_size,
                              hipStream_t stream)
{
    (void)in_sizes; (void)n_in; (void)out_size; (void)ws_size;
    const float* input   = (const float*)d_in[0];
    const float* feature = (const float*)d_in[1];
    // d_in[2] slider: unused by the reference computation
    const float* W1 = (const float*)d_in[3];
    const float* b1 = (const float*)d_in[4];
    const float* a1 = (const float*)d_in[5];
    const float* W2 = (const float*)d_in[6];
    const float* b2 = (const float*)d_in[7];
    const float* a2 = (const float*)d_in[8];
    const float* Wp = (const float*)d_in[9];
    const float* bp = (const float*)d_in[10];
    float* out = (float*)d_out;

    // workspace: pr 8MB | v1h 1MB | w2h 32KB | w1h 32KB | w10h 256B (~9.1MB)
    unsigned*  pr   = (unsigned*)d_ws;
    _Float16*  v1h  = (_Float16*)((char*)d_ws + (size_t)BT * DD * 8);
    _Float16*  w2h  = v1h + (size_t)BT * 128;
    _Float16*  w1h  = w2h + 16384;
    _Float16*  w10h = w1h + 16384;

    k_cvt  <<<dim3(16),   dim3(256), 0, stream>>>(W1, W2, w2h, w1h, w10h);
    k_prep2<<<dim3(256),  dim3(256), 0, stream>>>(feature, w1h, b1, v1h);
    k_main <<<dim3(2048), dim3(256), 0, stream>>>(input, b2, Wp, a1, a2,
                                                  v1h, w2h, w10h, pr);
    k_fin  <<<dim3(4096), dim3(256), 0, stream>>>(input, Wp, bp, pr, out);
}

// Round 9
// 66.838 us; speedup vs baseline: 1.1572x; 1.0286x over previous
//
#include <hip/hip_runtime.h>
#include <hip/hip_bf16.h>

// Problem constants (B,T,D,F) = (4,1024,256,128)
#define BT 4096
#define DD 256
#define CAT 129

typedef __attribute__((ext_vector_type(8))) _Float16 f16x8;
typedef __attribute__((ext_vector_type(4))) _Float16 f16x4;
typedef __attribute__((ext_vector_type(2))) _Float16 h2;
typedef __attribute__((ext_vector_type(4))) float f32x4;

// Opacity pin: forbids rematerialization, forces the value to stay in VGPRs.
#define PIN(x) asm volatile("" : "+v"(x))

static __device__ __forceinline__ h2 cvt_pk(float a, float b) {
    return __builtin_bit_cast(h2, __builtin_amdgcn_cvt_pkrtz(a, b));
}

static __device__ __forceinline__ float fdot2f(h2 a, h2 b, float c) {
#if __has_builtin(__builtin_amdgcn_fdot2)
    return __builtin_amdgcn_fdot2(__builtin_bit_cast(__fp16 __attribute__((ext_vector_type(2))), a),
                                  __builtin_bit_cast(__fp16 __attribute__((ext_vector_type(2))), b),
                                  c, false);
#else
    return fmaf((float)a[0], (float)b[0], fmaf((float)a[1], (float)b[1], c));
#endif
}

// ---------------------------------------------------------------------------
// k_cvt: blocks 0..7: W2 -> f16 LINEAR. blocks 8..15: W1[:,1:] -> f16
// XOR-swizzled (for k_prep2); block 8 also emits w10h = W1[:,0] in f16.
// ---------------------------------------------------------------------------
__global__ void __launch_bounds__(256) k_cvt(
    const float* __restrict__ W1, const float* __restrict__ W2,
    _Float16* __restrict__ w2h, _Float16* __restrict__ w1h,
    _Float16* __restrict__ w10h)
{
    const int t = threadIdx.x, b = blockIdx.x;
    if (b < 8) {
        #pragma unroll
        for (int i = 0; i < 8; ++i) {
            int idx = b * 2048 + i * 256 + t;       // g*128+f, linear
            w2h[idx] = (_Float16)W2[idx];
        }
    } else {
        int q = b - 8;
        #pragma unroll
        for (int i = 0; i < 8; ++i) {
            int idx = q * 2048 + i * 256 + t;       // f*128+c
            int f = idx >> 7, c = idx & 127;
            w1h[idx ^ ((f & 7) << 3)] = (_Float16)W1[f * CAT + 1 + c];
        }
        if (q == 0 && t < 128) w10h[t] = (_Float16)W1[t * CAT];
    }
}

// ---------------------------------------------------------------------------
// k_prep2: v1 = b1 + feature @ W1[:,1:]^T  (f16 MFMA GEMM, 16 rows/block),
// output stored as f16, linear [bt][f].
// ---------------------------------------------------------------------------
__global__ void __launch_bounds__(256) k_prep2(
    const float* __restrict__ feature, const _Float16* __restrict__ w1h,
    const float* __restrict__ b1p, _Float16* __restrict__ v1h)
{
    __shared__ __align__(16) _Float16 fS[2048];   // 16 x 128 f16, swizzled
    const int t = threadIdx.x;
    const int r0 = blockIdx.x * 16;

    {
        int e = t * 8;
        int r = e >> 7, c = e & 127;
        const float4* src = (const float4*)(feature + (size_t)(r0 + r) * 128 + c);
        float4 x0 = src[0], x1 = src[1];
        f16x8 hv;
        hv[0] = (_Float16)x0.x; hv[1] = (_Float16)x0.y;
        hv[2] = (_Float16)x0.z; hv[3] = (_Float16)x0.w;
        hv[4] = (_Float16)x1.x; hv[5] = (_Float16)x1.y;
        hv[6] = (_Float16)x1.z; hv[7] = (_Float16)x1.w;
        *(f16x8*)&fS[e ^ ((r & 7) << 3)] = hv;
    }
    __syncthreads();

    const int lane = t & 63, wv = t >> 6;
    const int l15 = lane & 15, l4 = lane >> 4;

    f16x8 bfr[2][4];
    float4 b1v[2];
    #pragma unroll
    for (int nt = 0; nt < 2; ++nt) {
        const int f0 = wv * 32 + nt * 16;
        b1v[nt] = *(const float4*)(b1p + f0 + l4 * 4);
        #pragma unroll
        for (int kc = 0; kc < 4; ++kc) {
            int f = f0 + l15, c = kc * 32 + l4 * 8;
            bfr[nt][kc] = *(const f16x8*)&w1h[(f * 128 + c) ^ ((f & 7) << 3)];
        }
    }

    const f32x4 fz = {0.f, 0.f, 0.f, 0.f};
    f32x4 acc[2] = {fz, fz};
    #pragma unroll
    for (int kc = 0; kc < 4; ++kc) {
        int r = l15, c = kc * 32 + l4 * 8;
        f16x8 afr = *(const f16x8*)&fS[(r * 128 + c) ^ ((r & 7) << 3)];
        #pragma unroll
        for (int nt = 0; nt < 2; ++nt)
            acc[nt] = __builtin_amdgcn_mfma_f32_16x16x32_f16(
                bfr[nt][kc], afr, acc[nt], 0, 0, 0);
    }

    #pragma unroll
    for (int nt = 0; nt < 2; ++nt) {
        f16x4 o;
        o[0] = (_Float16)(acc[nt][0] + ((const float*)&b1v[nt])[0]);
        o[1] = (_Float16)(acc[nt][1] + ((const float*)&b1v[nt])[1]);
        o[2] = (_Float16)(acc[nt][2] + ((const float*)&b1v[nt])[2]);
        o[3] = (_Float16)(acc[nt][3] + ((const float*)&b1v[nt])[3]);
        *(f16x4*)&v1h[(size_t)(r0 + l15) * 128 + wv * 32 + nt * 16 + l4 * 4] = o;
    }
}

// ---------------------------------------------------------------------------
// k_main: BARRIER-FREE, LDS-FREE. 8192 independent waves; wave W handles
// (bt = W>>1, cg = W&1): 16 iters of 16 rows x 64 g-cols. Persistent state
// (W2 frags bfr[4][4], v1/w10 lane-windows, b2 f32 C-init, packed Wp) is
// PINNED into VGPRs with inline-asm opacity so the compiler cannot
// rematerialize it as per-iteration memory loads (r7/r8 pathology).
// Per iter: in-reg h1 B-frag gen -> 16 MFMA (b2 enters as C of the first
// MFMA) -> packed epilogue -> 2-shfl reduce -> one packed-f16 partial store.
// ---------------------------------------------------------------------------
__global__ void __launch_bounds__(256, 3) k_main(
    const float* __restrict__ inp, const float* __restrict__ b2p,
    const float* __restrict__ Wp, const float* __restrict__ a1p,
    const float* __restrict__ a2p, const _Float16* __restrict__ v1h,
    const _Float16* __restrict__ w2h, const _Float16* __restrict__ w10h,
    unsigned* __restrict__ pr)
{
    const int tid  = threadIdx.x;
    const int lane = tid & 63, wv = tid >> 6;
    const int l15  = lane & 15, l4 = lane >> 4;
    const int W    = blockIdx.x * 4 + wv;     // 0..8191
    const int cg   = W & 1, bt = W >> 1;

    // ---- persistent W2 fragments: g = cg*64 + nt*16 + l15, f-window l4 ----
    f16x8 bfr[4][4];
    #pragma unroll
    for (int nt = 0; nt < 4; ++nt)
        #pragma unroll
        for (int kc = 0; kc < 4; ++kc) {
            bfr[nt][kc] = *(const f16x8*)
                &w2h[(cg * 64 + nt * 16 + l15) * 128 + kc * 32 + l4 * 8];
            PIN(bfr[nt][kc]);
        }

    // ---- v1 / w10 lane-windows (f = kc*32 + l4*8 .. +8) ----
    f16x8 v1pk[4], w10pk[4];
    #pragma unroll
    for (int kc = 0; kc < 4; ++kc) {
        v1pk[kc]  = *(const f16x8*)&v1h[(size_t)bt * 128 + kc * 32 + l4 * 8];
        w10pk[kc] = *(const f16x8*)&w10h[kc * 32 + l4 * 8];
        PIN(v1pk[kc]); PIN(w10pk[kc]);
    }

    // ---- b2 as f32 MFMA C-init + packed Wp slices, all pinned ----
    f32x4 accInit[4];
    h2 wpapk[4][2], wpbpk[4][2];
    #pragma unroll
    for (int nt = 0; nt < 4; ++nt) {
        const int g0 = cg * 64 + nt * 16 + l4 * 4;
        const float4 bv = *(const float4*)&b2p[g0];
        const float4 wa = *(const float4*)&Wp[g0];
        accInit[nt][0] = bv.x; accInit[nt][1] = bv.y;
        accInit[nt][2] = bv.z; accInit[nt][3] = bv.w;
        wpapk[nt][0] = cvt_pk(wa.x, wa.y);  wpapk[nt][1] = cvt_pk(wa.z, wa.w);
        wpbpk[nt][0] = cvt_pk(Wp[CAT + g0],     Wp[CAT + g0 + 1]);
        wpbpk[nt][1] = cvt_pk(Wp[CAT + g0 + 2], Wp[CAT + g0 + 3]);
        PIN(accInit[nt]);
        PIN(wpapk[nt][0]); PIN(wpapk[nt][1]);
        PIN(wpbpk[nt][0]); PIN(wpbpk[nt][1]);
    }

    const _Float16 a1s = (_Float16)a1p[0];
    const _Float16 a2s = (_Float16)a2p[0];
    f16x8 a1x8 = {a1s, a1s, a1s, a1s, a1s, a1s, a1s, a1s};
    h2 a2v; a2v[0] = a2s; a2v[1] = a2s;
    PIN(a1x8); PIN(a2v);

    const float* srow = inp + (size_t)bt * DD;
    float s_cur = srow[l15];

    #pragma unroll 2
    for (int it = 0; it < 16; ++it) {
        const float s_row = s_cur;
        if (it < 15) s_cur = srow[(it + 1) * 16 + l15];   // prefetch next

        // ---- h1 B-fragments generated in registers ----
        const _Float16 sh = (_Float16)s_row;
        const f16x8 s8 = {sh, sh, sh, sh, sh, sh, sh, sh};

        f32x4 acc[4];
        #pragma unroll
        for (int kc = 0; kc < 4; ++kc) {
            f16x8 h  = v1pk[kc] + w10pk[kc] * s8;
            f16x8 af = __builtin_elementwise_max(h, a1x8 * h);   // prelu, a1>=0
            #pragma unroll
            for (int nt = 0; nt < 4; ++nt)
                acc[nt] = __builtin_amdgcn_mfma_f32_16x16x32_f16(
                    bfr[nt][kc], af, (kc == 0) ? accInit[nt] : acc[nt], 0, 0, 0);
        }

        // ---- packed epilogue: prelu(a2), Wp dots (b2 already in acc) ----
        float p0 = 0.f, p1 = 0.f;
        #pragma unroll
        for (int nt = 0; nt < 4; ++nt) {
            h2 hh0 = cvt_pk(acc[nt][0], acc[nt][1]);
            h2 hh1 = cvt_pk(acc[nt][2], acc[nt][3]);
            h2 hp0 = __builtin_elementwise_max(hh0, a2v * hh0);
            h2 hp1 = __builtin_elementwise_max(hh1, a2v * hh1);
            p0 = fdot2f(wpapk[nt][0], hp0, p0);
            p0 = fdot2f(wpapk[nt][1], hp1, p0);
            p1 = fdot2f(wpbpk[nt][0], hp0, p1);
            p1 = fdot2f(wpbpk[nt][1], hp1, p1);
        }

        // ---- in-wave reduce over l4 (4 lanes, stride 16) ----
        p0 += __shfl_xor(p0, 16); p0 += __shfl_xor(p0, 32);
        p1 += __shfl_xor(p1, 16); p1 += __shfl_xor(p1, 32);

        if (l4 == 0)   // one packed f16 (p0,p1) per row per cg-half
            pr[((size_t)bt * DD + it * 16 + l15) * 2 + cg] =
                __builtin_bit_cast(unsigned, cvt_pk(p0, p1));
    }
}

// ---------------------------------------------------------------------------
// k_fin: combine cg halves + wpi*s + bp, sigmoid gate, write out. BW-bound.
// ---------------------------------------------------------------------------
__global__ void __launch_bounds__(256) k_fin(
    const float* __restrict__ inp, const float* __restrict__ Wp,
    const float* __restrict__ bpp, const unsigned* __restrict__ pr,
    float* __restrict__ out)
{
    const int i = blockIdx.x * 256 + threadIdx.x;   // 0 .. BT*DD-1
    const float wpi0 = Wp[128], wpi1 = Wp[CAT + 128];
    const float bp0  = bpp[0],  bp1  = bpp[1];

    const uint2 v = ((const uint2*)pr)[i];
    const h2 pa = __builtin_bit_cast(h2, v.x);   // cg0: (p0, p1)
    const h2 pb = __builtin_bit_cast(h2, v.y);   // cg1: (p0, p1)
    const float s = inp[i];

    const float e0 = (float)pa[0] + (float)pb[0] + wpi0 * s + bp0;
    const float e1 = (float)pa[1] + (float)pb[1] + wpi1 * s + bp1;
    const float gg = e0 / (1.f + __expf(-e1));
    out[i] = s * (1.f + gg);
}

// ---------------------------------------------------------------------------
extern "C" void kernel_launch(void* const* d_in, const int* in_sizes, int n_in,
                              void* d_out, int out_size, void* d_ws, size_t ws_size,
                              hipStream_t stream)
{
    (void)in_sizes; (void)n_in; (void)out_size; (void)ws_size;
    const float* input   = (const float*)d_in[0];
    const float* feature = (const float*)d_in[1];
    // d_in[2] slider: unused by the reference computation
    const float* W1 = (const float*)d_in[3];
    const float* b1 = (const float*)d_in[4];
    const float* a1 = (const float*)d_in[5];
    const float* W2 = (const float*)d_in[6];
    const float* b2 = (const float*)d_in[7];
    const float* a2 = (const float*)d_in[8];
    const float* Wp = (const float*)d_in[9];
    const float* bp = (const float*)d_in[10];
    float* out = (float*)d_out;

    // workspace: pr 8MB | v1h 1MB | w2h 32KB | w1h 32KB | w10h 256B (~9.1MB)
    unsigned*  pr   = (unsigned*)d_ws;
    _Float16*  v1h  = (_Float16*)((char*)d_ws + (size_t)BT * DD * 8);
    _Float16*  w2h  = v1h + (size_t)BT * 128;
    _Float16*  w1h  = w2h + 16384;
    _Float16*  w10h = w1h + 16384;

    k_cvt  <<<dim3(16),   dim3(256), 0, stream>>>(W1, W2, w2h, w1h, w10h);
    k_prep2<<<dim3(256),  dim3(256), 0, stream>>>(feature, w1h, b1, v1h);
    k_main <<<dim3(2048), dim3(256), 0, stream>>>(input, b2, Wp, a1, a2,
                                                  v1h, w2h, w10h, pr);
    k_fin  <<<dim3(4096), dim3(256), 0, stream>>>(input, Wp, bp, pr, out);
}